// Round 20
// baseline (150.999 us; speedup 1.0000x reference)
//
#include <hip/hip_runtime.h>
#include <math.h>

#define B_ 32
#define NODES_ 512
#define IN_ 256
#define OUT_ 128
#define CAPS_ 16
#define KW_ 5
#define M_ (B_*NODES_)            // 16384
#define N_ (KW_*OUT_)             // 640
#define NCH 32                    // node chunks of 16

typedef __attribute__((ext_vector_type(8))) short short8;
typedef __attribute__((ext_vector_type(4))) float f32x4;

// ---- workspace layout (bytes) ---- (round-5 proven: 51,642,368 total)
#define Y_BOFF   0
#define L_BOFF   41943040
#define V_BOFF   42991616
#define SP_BOFF  43253760
#define BT_SZ    (N_*IN_*2)       // 327,680 bytes each

#define YPAD 644                  // R18-proven (~2-way)
#define VPAD 130                  // v_perm [og][c*8]: conflict-free P1 v reads
#define APAD 84                   // NEW: 20*nd mod 32 -> 8 start banks (was 2: 8-way)

__device__ __forceinline__ float b2f(unsigned short u) {
  union { unsigned int i; float f; } c; c.i = ((unsigned int)u) << 16; return c.f;
}
__device__ __forceinline__ unsigned short f2b(float f) {
  union { float f; unsigned int i; } c; c.f = f;
  unsigned int u = c.i;
  u += 0x7fffu + ((u >> 16) & 1u);
  return (unsigned short)(u >> 16);
}
__device__ __forceinline__ void async_load16(const void* g, void* l) {
  __builtin_amdgcn_global_load_lds(
      (const __attribute__((address_space(1))) unsigned int*)g,
      (__attribute__((address_space(3))) unsigned int*)l, 16, 0, 0);
}

// ============================================================
// conv_w: split W into K-MAJOR bf16 hi/lo panels.
// ============================================================
__global__ __launch_bounds__(256) void conv_w(const float* __restrict__ W,
                                              unsigned short* __restrict__ bThi,
                                              unsigned short* __restrict__ bTlo) {
  int n = blockIdx.x;           // 0..639
  int i = threadIdx.x;          // 0..255
  int k = n >> 7, o = n & 127;
  float v = W[((size_t)k*IN_ + i)*OUT_ + o];
  unsigned short h = f2b(v);
  size_t dst = ((size_t)(i >> 3)*N_ + n)*8 + (i & 7);
  bThi[dst] = h;
  bTlo[dst] = f2b(v - b2f(h));
}

// ============================================================
// gemm_fn (R10-proven, ~11us): FULL-N blocks, coalesced reg-staged A,
// flat gload_lds B panels, split-bf16 3-pass MFMA.
// ============================================================
__global__ __launch_bounds__(512) void gemm_fn(const float* __restrict__ x,
                                               const unsigned short* __restrict__ bThi,
                                               const unsigned short* __restrict__ bTlo,
                                               float* __restrict__ y) {
  __shared__ float A_lds[8*64*4];      //  8 KB [cg][row][4f]
  __shared__ short Bh_lds[4*640*8];    // 40 KB [kg][n][8]
  __shared__ short Bl_lds[4*640*8];    // 40 KB
  const int t    = threadIdx.x;
  const int w    = t >> 6;
  const int lane = t & 63;
  const int lrow = lane & 15;
  const int lk   = lane >> 4;
  const int m0   = blockIdx.x * 64;
  const int wn0  = w * 80;
  const int arow = t >> 3;
  const int ac4  = t & 7;

  f32x4 acc[4][5];
  #pragma unroll
  for (int i=0;i<4;++i)
    #pragma unroll
    for (int j=0;j<5;++j) acc[i][j] = (f32x4){0.f,0.f,0.f,0.f};

  for (int kbi = 0; kbi < 8; ++kbi) {
    const int kb = kbi*32;
    const unsigned short* bh_src = bThi + (size_t)kbi*4*N_*8;
    const unsigned short* bl_src = bTlo + (size_t)kbi*4*N_*8;
    #pragma unroll
    for (int q=0; q<5; ++q) {
      int db = q*512 + w*64;
      async_load16(bh_src + (size_t)(db + lane)*8, &Bh_lds[db*8]);
      async_load16(bl_src + (size_t)(db + lane)*8, &Bl_lds[db*8]);
    }
    {
      float4 av = *(const float4*)(x + (size_t)(m0 + arow)*IN_ + kb + ac4*4);
      *(float4*)&A_lds[((ac4*64) + arow)*4] = av;
    }
    __syncthreads();

    short8 ah[4], al[4];
    #pragma unroll
    for (int mi=0; mi<4; ++mi) {
      int row = mi*16 + lrow;
      f32x4 a0 = *(const f32x4*)&A_lds[((2*lk  )*64 + row)*4];
      f32x4 a1 = *(const f32x4*)&A_lds[((2*lk+1)*64 + row)*4];
      #pragma unroll
      for (int j=0; j<8; ++j) {
        float f = (j < 4) ? a0[j] : a1[j-4];
        unsigned short h = f2b(f);
        ah[mi][j] = (short)h;
        al[mi][j] = (short)f2b(f - b2f(h));
      }
    }
    #pragma unroll
    for (int ni=0; ni<5; ++ni) {
      int nb = wn0 + ni*16 + lrow;
      short8 bh = *(const short8*)&Bh_lds[(lk*N_ + nb)*8];
      short8 bl = *(const short8*)&Bl_lds[(lk*N_ + nb)*8];
      #pragma unroll
      for (int mi=0; mi<4; ++mi) {
        acc[mi][ni] = __builtin_amdgcn_mfma_f32_16x16x32_bf16(bh, ah[mi], acc[mi][ni], 0, 0, 0);
        acc[mi][ni] = __builtin_amdgcn_mfma_f32_16x16x32_bf16(bh, al[mi], acc[mi][ni], 0, 0, 0);
        acc[mi][ni] = __builtin_amdgcn_mfma_f32_16x16x32_bf16(bl, ah[mi], acc[mi][ni], 0, 0, 0);
      }
    }
    __syncthreads();
  }

  #pragma unroll
  for (int mi=0; mi<4; ++mi) {
    int m = m0 + mi*16 + lrow;
    #pragma unroll
    for (int ni=0; ni<5; ++ni) {
      int nb = wn0 + ni*16 + lk*4;
      float4 o = {acc[mi][ni][0], acc[mi][ni][1], acc[mi][ni][2], acc[mi][ni][3]};
      *(float4*)(y + (size_t)m*N_ + nb) = o;
    }
  }
}

// ============================================================
// route2 (R19 + 2 fixes):
//  (1) APAD 84: P1's 20 aT reads were 8-way bank-conflicted (stride
//      80 -> start banks {0,16}); 84 spreads over 8 start banks (~free).
//  (2) sh_cwa pass removed: P2 multiplies cw*aT inline (broadcast
//      reads) -> -15 LDS ops/thread, -1 barrier/chunk, -5 KB LDS.
// Phase math identical to R18/R19.
// ============================================================
__global__ __launch_bounds__(256) void route2(const float* __restrict__ y,
                                              const float* __restrict__ alpha,
                                              const float* __restrict__ contrib,
                                              float* __restrict__ logits,
                                              const float* __restrict__ vin,
                                              float* __restrict__ s_part,
                                              int mode) {
  __shared__ __align__(16) float sh_y[16*YPAD];   // 41.2 KB (red overlay after P2)
  __shared__ __align__(16) float sh_v[16*VPAD];   //  8.3 KB v_perm [og][c*8]
  __shared__ __align__(16) float sh_aT[16*APAD];  //  5.4 KB [nd][k*16+c], pad 84
  __shared__ __align__(16) float sh_cw[256];      //  1 KB  [nd*16+c]

  const int t  = threadIdx.x;
  const int cp = blockIdx.x;   // 0..15 (chunk pair)
  const int b  = blockIdx.y;   // 0..31

  // ---- stage v_perm once per sweep (mode>=1) / cw init (mode 0) ----
  if (mode >= 1) {
    const float* vbase = vin + (size_t)b*CAPS_*OUT_;
    #pragma unroll
    for (int q=0; q<2; ++q) {
      int flat = (t + q*256)*4;
      int c = flat >> 7, o = flat & 127;
      float4 vv = *(const float4*)(vbase + flat);
      *(float4*)&sh_v[(o >> 3)*VPAD + c*8 + (o & 7)] = vv;
    }
  } else {
    sh_cw[t] = 0.0625f;
  }

  // ---- preload chunk0 y into regs ----
  float4 yst[10], ynx[10];
  {
    const float* yb0 = y + ((size_t)(b*NODES_ + cp*32))*N_;
    #pragma unroll
    for (int q=0; q<10; ++q) yst[q] = *(const float4*)(yb0 + (size_t)(t + q*256)*4);
  }

  #pragma unroll
  for (int hh = 0; hh < 2; ++hh) {
    const int ch = cp*2 + hh;
    const int n0 = ch*16;

    // ---- commit y regs -> padded sh_y; stage aT(ch) ----
    #pragma unroll
    for (int q=0; q<10; ++q) {
      int flat = (t + q*256)*4;
      int nd   = flat / 640;
      int rem  = flat - nd*640;
      float4 src = (hh == 0) ? yst[q] : ynx[q];
      *(float4*)&sh_y[nd*YPAD + rem] = src;
    }
    {
      const float* abase = alpha + (size_t)n0*CAPS_*KW_;
      for (int i = t; i < 320; i += 256) {
        float4 av = *(const float4*)(abase + i*4);
        int flat = i*4;
        int nd   = flat / 80;
        int rem  = flat - nd*80;
        #pragma unroll
        for (int e=0; e<4; ++e) {
          int r = rem + e;
          int c = r / 5;
          int k = r - c*5;
          sh_aT[nd*APAD + k*16 + c] = av[e];
        }
      }
    }
    if (mode == 0) {
      int nd = t >> 4, c = t & 15;
      logits[((size_t)b*CAPS_ + c)*NODES_ + n0 + nd] = contrib[(size_t)b*NODES_ + n0 + nd];
    }
    __syncthreads();

    // ---- issue chunk1's global y loads (hide under chunk0 compute) ----
    if (hh == 0) {
      const float* yb1 = y + ((size_t)(b*NODES_ + cp*32 + 16))*N_;
      #pragma unroll
      for (int q=0; q<10; ++q) ynx[q] = *(const float4*)(yb1 + (size_t)(t + q*256)*4);
    }

    if (mode >= 1) {
      // ---- phase 1: thread = (nd = t>>4, og = t&15) ----
      const int nd = t >> 4, og = t & 15;
      float4 yq[5][2];
      #pragma unroll
      for (int k=0; k<5; ++k) {
        yq[k][0] = *(const float4*)&sh_y[nd*YPAD + k*128 + og*8];
        yq[k][1] = *(const float4*)&sh_y[nd*YPAD + k*128 + og*8 + 4];
      }
      float p[16];
      #pragma unroll
      for (int c=0;c<16;++c) p[c] = 0.f;
      #pragma unroll
      for (int cq=0; cq<4; ++cq) {
        float4 a5[5];
        #pragma unroll
        for (int k=0;k<5;++k) a5[k] = *(const float4*)&sh_aT[nd*APAD + k*16 + cq*4];
        #pragma unroll
        for (int cl=0; cl<4; ++cl) {
          int c = cq*4 + cl;
          float4 v0 = *(const float4*)&sh_v[og*VPAD + c*8];
          float4 v1 = *(const float4*)&sh_v[og*VPAD + c*8 + 4];
          float d[5];
          #pragma unroll
          for (int k=0;k<5;++k) {
            d[k] = yq[k][0].x*v0.x + yq[k][0].y*v0.y + yq[k][0].z*v0.z + yq[k][0].w*v0.w
                 + yq[k][1].x*v1.x + yq[k][1].y*v1.y + yq[k][1].z*v1.z + yq[k][1].w*v1.w;
          }
          p[c] += a5[0][cl]*d[0] + a5[1][cl]*d[1] + a5[2][cl]*d[2]
                + a5[3][cl]*d[3] + a5[4][cl]*d[4];
        }
      }
      // butterfly reduce-scatter: lane og ends with cap og
      float q8[8];
      #pragma unroll
      for (int j=0;j<8;++j) {
        float a = p[2*j], bb = p[2*j+1];
        float mine = (og & 1) ? bb : a;
        float othr = (og & 1) ? a  : bb;
        q8[j] = mine + __shfl_xor(othr, 1, 64);
      }
      float r4[4];
      #pragma unroll
      for (int j=0;j<4;++j) {
        float a = q8[2*j], bb = q8[2*j+1];
        float mine = (og & 2) ? bb : a;
        float othr = (og & 2) ? a  : bb;
        r4[j] = mine + __shfl_xor(othr, 2, 64);
      }
      float s2[2];
      #pragma unroll
      for (int j=0;j<2;++j) {
        float a = r4[2*j], bb = r4[2*j+1];
        float mine = (og & 4) ? bb : a;
        float othr = (og & 4) ? a  : bb;
        s2[j] = mine + __shfl_xor(othr, 4, 64);
      }
      float aa = s2[0], bb2 = s2[1];
      float mine4 = (og & 8) ? bb2 : aa;
      float othr4 = (og & 8) ? aa  : bb2;
      float fin = mine4 + __shfl_xor(othr4, 8, 64);

      float lold = logits[((size_t)b*CAPS_ + og)*NODES_ + n0 + nd];
      float newl = lold + fin;
      logits[((size_t)b*CAPS_ + og)*NODES_ + n0 + nd] = newl;
      float m = newl;
      m = fmaxf(m, __shfl_xor(m, 1, 64));
      m = fmaxf(m, __shfl_xor(m, 2, 64));
      m = fmaxf(m, __shfl_xor(m, 4, 64));
      m = fmaxf(m, __shfl_xor(m, 8, 64));
      float e = __expf(newl - m);
      float ssum = e;
      ssum += __shfl_xor(ssum, 1, 64);
      ssum += __shfl_xor(ssum, 2, 64);
      ssum += __shfl_xor(ssum, 4, 64);
      ssum += __shfl_xor(ssum, 8, 64);
      sh_cw[nd*16 + og] = e / ssum;
    }
    __syncthreads();   // cw ready (P1) / y committed (mode 0)

    // ---- phase 2: thread = (oq = t&31, cg = (t>>5)&1, ng = t>>6) ----
    // cw*aT multiplied INLINE (broadcast reads; no cwa pass).
    {
      const int oq = t & 31;
      const int cg = (t >> 5) & 1;
      const int ng = t >> 6;
      float acc[8][4];
      #pragma unroll
      for (int j=0;j<8;++j)
        #pragma unroll
        for (int oo=0;oo<4;++oo) acc[j][oo] = 0.f;

      #pragma unroll
      for (int ii=0; ii<4; ++ii) {
        int nd = ng + ii*4;
        float4 cw0 = *(const float4*)&sh_cw[nd*16 + cg*8];
        float4 cw1 = *(const float4*)&sh_cw[nd*16 + cg*8 + 4];
        float cwv[8] = {cw0.x,cw0.y,cw0.z,cw0.w,cw1.x,cw1.y,cw1.z,cw1.w};
        #pragma unroll
        for (int k=0; k<5; ++k) {
          float4 yq  = *(const float4*)&sh_y[nd*YPAD + k*128 + oq*4];
          float4 a0  = *(const float4*)&sh_aT[nd*APAD + k*16 + cg*8];
          float4 a1  = *(const float4*)&sh_aT[nd*APAD + k*16 + cg*8 + 4];
          float av8[8] = {a0.x,a0.y,a0.z,a0.w,a1.x,a1.y,a1.z,a1.w};
          float yv[4]  = {yq.x,yq.y,yq.z,yq.w};
          #pragma unroll
          for (int j=0;j<8;++j) {
            float ce = cwv[j]*av8[j];
            #pragma unroll
            for (int oo=0;oo<4;++oo)
              acc[j][oo] += ce*yv[oo];
          }
        }
      }
      __syncthreads();                 // all P2 reads of sh_y complete
      float* red = sh_y;               // 32 KB overlay [ng][c][o]
      #pragma unroll
      for (int j=0;j<8;++j) {
        float4 w4 = {acc[j][0], acc[j][1], acc[j][2], acc[j][3]};
        *(float4*)&red[(size_t)ng*2048 + (cg*8 + j)*128 + oq*4] = w4;
      }
      __syncthreads();
      const int c2 = t >> 4;
      const int o2 = (t & 15) * 8;
      float4 r0 = {0,0,0,0}, r1 = {0,0,0,0};
      #pragma unroll
      for (int g=0; g<4; ++g) {
        float4 q0 = *(const float4*)&red[(size_t)g*2048 + c2*128 + o2];
        float4 q1 = *(const float4*)&red[(size_t)g*2048 + c2*128 + o2 + 4];
        r0.x += q0.x; r0.y += q0.y; r0.z += q0.z; r0.w += q0.w;
        r1.x += q1.x; r1.y += q1.y; r1.z += q1.z; r1.w += q1.w;
      }
      float* spb = s_part + ((size_t)(b*NCH + ch)*CAPS_ + c2)*OUT_ + o2;
      *(float4*)(spb)     = r0;
      *(float4*)(spb + 4) = r1;
    }
    __syncthreads();   // red (= sh_y) fully consumed before chunk1 commit
  }
}

// ============================================================
// squash_k: reduce s_part over chunks, squash, write v (or out)
// ============================================================
__global__ __launch_bounds__(128) void squash_k(const float* __restrict__ s_part,
                                                float* __restrict__ out) {
  const int bc = blockIdx.x;       // b*16+c
  const int o  = threadIdx.x;      // 0..127
  const int b = bc >> 4, c = bc & 15;
  const float* sp = s_part + ((size_t)(b*NCH)*CAPS_ + c)*OUT_ + o;
  float s = 0.f;
  #pragma unroll
  for (int ch=0; ch<NCH; ++ch) s += sp[(size_t)ch*CAPS_*OUT_];
  float ss = s*s;
  #pragma unroll
  for (int off=32; off>0; off>>=1) ss += __shfl_down(ss, off, 64);
  __shared__ float red[2];
  if ((o & 63) == 0) red[o>>6] = ss;
  __syncthreads();
  float sn = red[0] + red[1];
  float scale = (sn/(1.f+sn)) / (sqrtf(sn)+1e-8f);
  out[(size_t)bc*OUT_ + o] = scale*s;
}

// ============================================================
extern "C" void kernel_launch(void* const* d_in, const int* in_sizes, int n_in,
                              void* d_out, int out_size, void* d_ws, size_t ws_size,
                              hipStream_t stream) {
  const float* x       = (const float*)d_in[0];
  const float* contrib = (const float*)d_in[1];
  const float* W       = (const float*)d_in[2];
  const float* alpha   = (const float*)d_in[3];
  float* out = (float*)d_out;
  char*  wsb = (char*)d_ws;

  float* y             = (float*)(wsb + Y_BOFF);
  float* logits        = (float*)(wsb + L_BOFF);
  float* v             = (float*)(wsb + V_BOFF);
  float* s_part        = (float*)(wsb + SP_BOFF);
  // bT hi/lo alias the s_part region (consumed before s_part first written)
  unsigned short* bThi = (unsigned short*)(wsb + SP_BOFF);
  unsigned short* bTlo = (unsigned short*)(wsb + SP_BOFF + BT_SZ);

  conv_w<<<N_, 256, 0, stream>>>(W, bThi, bTlo);
  gemm_fn<<<M_/64, 512, 0, stream>>>(x, bThi, bTlo, y);

  route2<<<dim3(NCH/2, B_), 256, 0, stream>>>(y, alpha, contrib, logits, v, s_part, 0);
  squash_k<<<B_*CAPS_, 128, 0, stream>>>(s_part, v);

  for (int it=0; it<3; ++it) {
    route2<<<dim3(NCH/2, B_), 256, 0, stream>>>(y, alpha, contrib, logits, v, s_part, 1);
    squash_k<<<B_*CAPS_, 128, 0, stream>>>(s_part, (it==2) ? out : v);
  }
}

// Round 21
// 129.226 us; speedup vs baseline: 1.1685x; 1.1685x over previous
//
#include <hip/hip_runtime.h>
#include <math.h>

#define B_ 32
#define NODES_ 512
#define IN_ 256
#define OUT_ 128
#define CAPS_ 16
#define KW_ 5
#define M_ (B_*NODES_)            // 16384
#define N_ (KW_*OUT_)             // 640
#define NCH 32                    // node chunks of 16

typedef __attribute__((ext_vector_type(8))) short short8;
typedef __attribute__((ext_vector_type(4))) float f32x4;

// ---- workspace layout (bytes) ---- (round-5 proven: 51,642,368 total)
#define Y_BOFF   0
#define L_BOFF   41943040
#define V_BOFF   42991616
#define SP_BOFF  43253760
#define BT_SZ    (N_*IN_*2)       // 327,680 bytes each

#define YPAD 644                  // 644%32==4 -> 4(nd+2og) start-banks: ~2-way (free)

__device__ __forceinline__ float b2f(unsigned short u) {
  union { unsigned int i; float f; } c; c.i = ((unsigned int)u) << 16; return c.f;
}
__device__ __forceinline__ unsigned short f2b(float f) {
  union { float f; unsigned int i; } c; c.f = f;
  unsigned int u = c.i;
  u += 0x7fffu + ((u >> 16) & 1u);
  return (unsigned short)(u >> 16);
}
__device__ __forceinline__ void async_load16(const void* g, void* l) {
  __builtin_amdgcn_global_load_lds(
      (const __attribute__((address_space(1))) unsigned int*)g,
      (__attribute__((address_space(3))) unsigned int*)l, 16, 0, 0);
}

// ============================================================
// conv_w: split W into K-MAJOR bf16 hi/lo panels.
// ============================================================
__global__ __launch_bounds__(256) void conv_w(const float* __restrict__ W,
                                              unsigned short* __restrict__ bThi,
                                              unsigned short* __restrict__ bTlo) {
  int n = blockIdx.x;           // 0..639
  int i = threadIdx.x;          // 0..255
  int k = n >> 7, o = n & 127;
  float v = W[((size_t)k*IN_ + i)*OUT_ + o];
  unsigned short h = f2b(v);
  size_t dst = ((size_t)(i >> 3)*N_ + n)*8 + (i & 7);
  bThi[dst] = h;
  bTlo[dst] = f2b(v - b2f(h));
}

// ============================================================
// gemm_fn (R10-proven, ~11us): FULL-N blocks, coalesced reg-staged A,
// flat gload_lds B panels, split-bf16 3-pass MFMA.
// ============================================================
__global__ __launch_bounds__(512) void gemm_fn(const float* __restrict__ x,
                                               const unsigned short* __restrict__ bThi,
                                               const unsigned short* __restrict__ bTlo,
                                               float* __restrict__ y) {
  __shared__ float A_lds[8*64*4];      //  8 KB [cg][row][4f]
  __shared__ short Bh_lds[4*640*8];    // 40 KB [kg][n][8]
  __shared__ short Bl_lds[4*640*8];    // 40 KB
  const int t    = threadIdx.x;
  const int w    = t >> 6;
  const int lane = t & 63;
  const int lrow = lane & 15;
  const int lk   = lane >> 4;
  const int m0   = blockIdx.x * 64;
  const int wn0  = w * 80;
  const int arow = t >> 3;
  const int ac4  = t & 7;

  f32x4 acc[4][5];
  #pragma unroll
  for (int i=0;i<4;++i)
    #pragma unroll
    for (int j=0;j<5;++j) acc[i][j] = (f32x4){0.f,0.f,0.f,0.f};

  for (int kbi = 0; kbi < 8; ++kbi) {
    const int kb = kbi*32;
    const unsigned short* bh_src = bThi + (size_t)kbi*4*N_*8;
    const unsigned short* bl_src = bTlo + (size_t)kbi*4*N_*8;
    #pragma unroll
    for (int q=0; q<5; ++q) {
      int db = q*512 + w*64;
      async_load16(bh_src + (size_t)(db + lane)*8, &Bh_lds[db*8]);
      async_load16(bl_src + (size_t)(db + lane)*8, &Bl_lds[db*8]);
    }
    {
      float4 av = *(const float4*)(x + (size_t)(m0 + arow)*IN_ + kb + ac4*4);
      *(float4*)&A_lds[((ac4*64) + arow)*4] = av;
    }
    __syncthreads();

    short8 ah[4], al[4];
    #pragma unroll
    for (int mi=0; mi<4; ++mi) {
      int row = mi*16 + lrow;
      f32x4 a0 = *(const f32x4*)&A_lds[((2*lk  )*64 + row)*4];
      f32x4 a1 = *(const f32x4*)&A_lds[((2*lk+1)*64 + row)*4];
      #pragma unroll
      for (int j=0; j<8; ++j) {
        float f = (j < 4) ? a0[j] : a1[j-4];
        unsigned short h = f2b(f);
        ah[mi][j] = (short)h;
        al[mi][j] = (short)f2b(f - b2f(h));
      }
    }
    #pragma unroll
    for (int ni=0; ni<5; ++ni) {
      int nb = wn0 + ni*16 + lrow;
      short8 bh = *(const short8*)&Bh_lds[(lk*N_ + nb)*8];
      short8 bl = *(const short8*)&Bl_lds[(lk*N_ + nb)*8];
      #pragma unroll
      for (int mi=0; mi<4; ++mi) {
        acc[mi][ni] = __builtin_amdgcn_mfma_f32_16x16x32_bf16(bh, ah[mi], acc[mi][ni], 0, 0, 0);
        acc[mi][ni] = __builtin_amdgcn_mfma_f32_16x16x32_bf16(bh, al[mi], acc[mi][ni], 0, 0, 0);
        acc[mi][ni] = __builtin_amdgcn_mfma_f32_16x16x32_bf16(bl, ah[mi], acc[mi][ni], 0, 0, 0);
      }
    }
    __syncthreads();
  }

  #pragma unroll
  for (int mi=0; mi<4; ++mi) {
    int m = m0 + mi*16 + lrow;
    #pragma unroll
    for (int ni=0; ni<5; ++ni) {
      int nb = wn0 + ni*16 + lk*4;
      float4 o = {acc[mi][ni][0], acc[mi][ni][1], acc[mi][ni][2], acc[mi][ni][3]};
      *(float4*)(y + (size_t)m*N_ + nb) = o;
    }
  }
}

// ============================================================
// route_rs (R18-proven, best 129.0us): distinct-lane LDS reads in
// both phases; phase-1 cap-reduce = butterfly REDUCE-SCATTER;
// YPAD 644 (~2-way banks).
// ============================================================
__global__ __launch_bounds__(256) void route_rs(const float* __restrict__ y,
                                                const float* __restrict__ alpha,
                                                const float* __restrict__ contrib,
                                                float* __restrict__ logits,
                                                const float* __restrict__ vin,
                                                float* __restrict__ s_part,
                                                int mode) {
  __shared__ __align__(16) float sh_y[16*YPAD];   // 41.2 KB (red overlay after P2)
  __shared__ __align__(16) float sh_v[16*132];    //  8.4 KB [cap][o]
  __shared__ __align__(16) float sh_aT[16*80];    //  5 KB  [nd][k*16+c]
  __shared__ __align__(16) float sh_cwa[16*80];   //  5 KB  [nd][k*16+c]
  __shared__ float sh_cw[256];                    //  1 KB  [nd*16+c]

  const int t  = threadIdx.x;
  const int ch = blockIdx.x;   // 0..31
  const int b  = blockIdx.y;   // 0..31
  const int n0 = ch*16;

  // ---- stage y: reg round-trip into padded rows ----
  const float* ybase = y + ((size_t)(b*NODES_ + n0))*N_;
  float4 yst[10];
  #pragma unroll
  for (int q=0; q<10; ++q) yst[q] = *(const float4*)(ybase + (size_t)(t + q*256)*4);
  #pragma unroll
  for (int q=0; q<10; ++q) {
    int flat = (t + q*256)*4;
    int nd   = flat / 640;
    int rem  = flat - nd*640;
    *(float4*)&sh_y[nd*YPAD + rem] = yst[q];
  }
  // ---- stage alpha TRANSPOSED: aT[nd][k*16+c] = alpha[n0+nd][c][k] ----
  const float* abase = alpha + (size_t)n0*CAPS_*KW_;
  for (int i = t; i < 320; i += 256) {
    float4 av = *(const float4*)(abase + i*4);
    int flat = i*4;
    int nd   = flat / 80;
    int rem  = flat - nd*80;
    #pragma unroll
    for (int e=0; e<4; ++e) {
      int r = rem + e;
      int c = r / 5;
      int k = r - c*5;
      sh_aT[nd*80 + k*16 + c] = av[e];
    }
  }
  if (mode >= 1) {
    const float* vbase = vin + (size_t)b*CAPS_*OUT_;
    #pragma unroll
    for (int q=0; q<2; ++q) {
      int flat = (t + q*256)*4;
      int c = flat >> 7, o = flat & 127;
      float4 vv = *(const float4*)(vbase + flat);
      *(float4*)&sh_v[c*132 + o] = vv;
    }
  } else {
    sh_cw[t] = 0.0625f;
    int nd = t >> 4, c = t & 15;
    logits[((size_t)b*CAPS_ + c)*NODES_ + n0 + nd] = contrib[(size_t)b*NODES_ + n0 + nd];
  }
  __syncthreads();

  if (mode >= 1) {
    // ---- phase 1: thread = (nd = t>>4, og = t&15), o-range og*8..+7 ----
    const int nd = t >> 4, og = t & 15;
    float4 yq[5][2];
    #pragma unroll
    for (int k=0; k<5; ++k) {
      yq[k][0] = *(const float4*)&sh_y[nd*YPAD + k*128 + og*8];
      yq[k][1] = *(const float4*)&sh_y[nd*YPAD + k*128 + og*8 + 4];
    }
    float p[16];
    #pragma unroll
    for (int c=0;c<16;++c) p[c] = 0.f;
    #pragma unroll
    for (int cq=0; cq<4; ++cq) {
      float4 a5[5];
      #pragma unroll
      for (int k=0;k<5;++k) a5[k] = *(const float4*)&sh_aT[nd*80 + k*16 + cq*4];
      #pragma unroll
      for (int cl=0; cl<4; ++cl) {
        int c = cq*4 + cl;
        float4 v0 = *(const float4*)&sh_v[c*132 + og*8];
        float4 v1 = *(const float4*)&sh_v[c*132 + og*8 + 4];
        float d[5];
        #pragma unroll
        for (int k=0;k<5;++k) {
          d[k] = yq[k][0].x*v0.x + yq[k][0].y*v0.y + yq[k][0].z*v0.z + yq[k][0].w*v0.w
               + yq[k][1].x*v1.x + yq[k][1].y*v1.y + yq[k][1].z*v1.z + yq[k][1].w*v1.w;
        }
        p[c] += a5[0][cl]*d[0] + a5[1][cl]*d[1] + a5[2][cl]*d[2]
              + a5[3][cl]*d[3] + a5[4][cl]*d[4];
      }
    }
    // ---- butterfly REDUCE-SCATTER over 16 og-lanes: lane og -> cap og ----
    float q8[8];
    #pragma unroll
    for (int j=0;j<8;++j) {
      float a = p[2*j], bb = p[2*j+1];
      float mine = (og & 1) ? bb : a;
      float othr = (og & 1) ? a  : bb;
      q8[j] = mine + __shfl_xor(othr, 1, 64);
    }
    float r4[4];
    #pragma unroll
    for (int j=0;j<4;++j) {
      float a = q8[2*j], bb = q8[2*j+1];
      float mine = (og & 2) ? bb : a;
      float othr = (og & 2) ? a  : bb;
      r4[j] = mine + __shfl_xor(othr, 2, 64);
    }
    float s2[2];
    #pragma unroll
    for (int j=0;j<2;++j) {
      float a = r4[2*j], bb = r4[2*j+1];
      float mine = (og & 4) ? bb : a;
      float othr = (og & 4) ? a  : bb;
      s2[j] = mine + __shfl_xor(othr, 4, 64);
    }
    float aa = s2[0], bb2 = s2[1];
    float mine4 = (og & 8) ? bb2 : aa;
    float othr4 = (og & 8) ? aa  : bb2;
    float fin = mine4 + __shfl_xor(othr4, 8, 64);

    float lold = logits[((size_t)b*CAPS_ + og)*NODES_ + n0 + nd];
    float newl = lold + fin;
    logits[((size_t)b*CAPS_ + og)*NODES_ + n0 + nd] = newl;
    // softmax over caps (= og lanes of same nd)
    float m = newl;
    m = fmaxf(m, __shfl_xor(m, 1, 64));
    m = fmaxf(m, __shfl_xor(m, 2, 64));
    m = fmaxf(m, __shfl_xor(m, 4, 64));
    m = fmaxf(m, __shfl_xor(m, 8, 64));
    float e = __expf(newl - m);
    float ssum = e;
    ssum += __shfl_xor(ssum, 1, 64);
    ssum += __shfl_xor(ssum, 2, 64);
    ssum += __shfl_xor(ssum, 4, 64);
    ssum += __shfl_xor(ssum, 8, 64);
    sh_cw[nd*16 + og] = e / ssum;
  }
  __syncthreads();

  // ---- cwa[nd][k*16+c] = cw[nd][c] * aT ----
  #pragma unroll
  for (int i = t; i < 1280; i += 256) {
    int nd = i / 80;
    int c  = i & 15;               // i%80's low 4 bits == c (16 | 80 layout)
    sh_cwa[i] = sh_cw[nd*16 + c] * sh_aT[i];
  }
  __syncthreads();

  // ---- phase 2: thread = (oq = t&31, cg = (t>>5)&1, ng = t>>6) ----
  {
    const int oq = t & 31;
    const int cg = (t >> 5) & 1;
    const int ng = t >> 6;          // wave id; nds {ng, ng+4, ng+8, ng+12}
    float acc[8][4];
    #pragma unroll
    for (int j=0;j<8;++j)
      #pragma unroll
      for (int oo=0;oo<4;++oo) acc[j][oo] = 0.f;

    #pragma unroll
    for (int ii=0; ii<4; ++ii) {
      int nd = ng + ii*4;
      #pragma unroll
      for (int k=0; k<5; ++k) {
        float4 yq  = *(const float4*)&sh_y[nd*YPAD + k*128 + oq*4];
        float4 ca0 = *(const float4*)&sh_cwa[nd*80 + k*16 + cg*8];
        float4 ca1 = *(const float4*)&sh_cwa[nd*80 + k*16 + cg*8 + 4];
        float cav[8] = {ca0.x,ca0.y,ca0.z,ca0.w,ca1.x,ca1.y,ca1.z,ca1.w};
        float yv[4]  = {yq.x,yq.y,yq.z,yq.w};
        #pragma unroll
        for (int j=0;j<8;++j)
          #pragma unroll
          for (int oo=0;oo<4;++oo)
            acc[j][oo] += cav[j]*yv[oo];
      }
    }
    __syncthreads();                 // all P2 reads of sh_y complete
    // red overlay on sh_y: red[ng][c][o], 4*16*128 floats = 32 KB
    float* red = sh_y;
    #pragma unroll
    for (int j=0;j<8;++j) {
      float4 w4 = {acc[j][0], acc[j][1], acc[j][2], acc[j][3]};
      *(float4*)&red[(size_t)ng*2048 + (cg*8 + j)*128 + oq*4] = w4;
    }
    __syncthreads();
    // final reduce over ng: thread = (c2 = t>>4, o2 = (t&15)*8)
    const int c2 = t >> 4;
    const int o2 = (t & 15) * 8;
    float4 r0 = {0,0,0,0}, r1 = {0,0,0,0};
    #pragma unroll
    for (int g=0; g<4; ++g) {
      float4 q0 = *(const float4*)&red[(size_t)g*2048 + c2*128 + o2];
      float4 q1 = *(const float4*)&red[(size_t)g*2048 + c2*128 + o2 + 4];
      r0.x += q0.x; r0.y += q0.y; r0.z += q0.z; r0.w += q0.w;
      r1.x += q1.x; r1.y += q1.y; r1.z += q1.z; r1.w += q1.w;
    }
    float* spb = s_part + ((size_t)(b*NCH + ch)*CAPS_ + c2)*OUT_ + o2;
    *(float4*)(spb)     = r0;
    *(float4*)(spb + 4) = r1;
  }
}

// ============================================================
// squash_k: reduce s_part over chunks, squash, write v (or out)
// ============================================================
__global__ __launch_bounds__(128) void squash_k(const float* __restrict__ s_part,
                                                float* __restrict__ out) {
  const int bc = blockIdx.x;       // b*16+c
  const int o  = threadIdx.x;      // 0..127
  const int b = bc >> 4, c = bc & 15;
  const float* sp = s_part + ((size_t)(b*NCH)*CAPS_ + c)*OUT_ + o;
  float s = 0.f;
  #pragma unroll
  for (int ch=0; ch<NCH; ++ch) s += sp[(size_t)ch*CAPS_*OUT_];
  float ss = s*s;
  #pragma unroll
  for (int off=32; off>0; off>>=1) ss += __shfl_down(ss, off, 64);
  __shared__ float red[2];
  if ((o & 63) == 0) red[o>>6] = ss;
  __syncthreads();
  float sn = red[0] + red[1];
  float scale = (sn/(1.f+sn)) / (sqrtf(sn)+1e-8f);
  out[(size_t)bc*OUT_ + o] = scale*s;
}

// ============================================================
extern "C" void kernel_launch(void* const* d_in, const int* in_sizes, int n_in,
                              void* d_out, int out_size, void* d_ws, size_t ws_size,
                              hipStream_t stream) {
  const float* x       = (const float*)d_in[0];
  const float* contrib = (const float*)d_in[1];
  const float* W       = (const float*)d_in[2];
  const float* alpha   = (const float*)d_in[3];
  float* out = (float*)d_out;
  char*  wsb = (char*)d_ws;

  float* y             = (float*)(wsb + Y_BOFF);
  float* logits        = (float*)(wsb + L_BOFF);
  float* v             = (float*)(wsb + V_BOFF);
  float* s_part        = (float*)(wsb + SP_BOFF);
  // bT hi/lo alias the s_part region (consumed before s_part first written)
  unsigned short* bThi = (unsigned short*)(wsb + SP_BOFF);
  unsigned short* bTlo = (unsigned short*)(wsb + SP_BOFF + BT_SZ);

  conv_w<<<N_, 256, 0, stream>>>(W, bThi, bTlo);
  gemm_fn<<<M_/64, 512, 0, stream>>>(x, bThi, bTlo, y);

  route_rs<<<dim3(NCH, B_), 256, 0, stream>>>(y, alpha, contrib, logits, v, s_part, 0);
  squash_k<<<B_*CAPS_, 128, 0, stream>>>(s_part, v);

  for (int it=0; it<3; ++it) {
    route_rs<<<dim3(NCH, B_), 256, 0, stream>>>(y, alpha, contrib, logits, v, s_part, 1);
    squash_k<<<B_*CAPS_, 128, 0, stream>>>(s_part, (it==2) ? out : v);
  }
}